// Round 7
// baseline (630.670 us; speedup 1.0000x reference)
//
#include <hip/hip_runtime.h>
#include <hip/hip_bf16.h>

constexpr int TT = 512, BB = 2048, NOUT = 8;
constexpr size_t DSTRIDE = (size_t)BB * TT * 24;   // f16 elems per dir region

typedef __attribute__((ext_vector_type(8))) _Float16 f16x8;
typedef __attribute__((ext_vector_type(4))) float f32x4;
typedef __attribute__((ext_vector_type(2))) _Float16 f16x2;

// fast device math: v_exp_f32 / v_rcp_f32 (1-ulp approx, no div sequence)
__device__ __forceinline__ float sigm(float x) {
    float e = __builtin_amdgcn_exp2f(x * -1.4426950408889634f);
    return __builtin_amdgcn_rcpf(1.f + e);
}
__device__ __forceinline__ float tanh_(float x) {
    float e = __builtin_amdgcn_exp2f(x * 2.8853900817779268f);
    return __builtin_fmaf(-2.f, __builtin_amdgcn_rcpf(e + 1.f), 1.f);
}
__device__ __forceinline__ f16x2 asf16x2(unsigned v) {
    f16x2 r; __builtin_memcpy(&r, &v, 4); return r;
}
// v_cvt_pkrtz_f16_f32 with a bit-cast to our f16x2 (builtin returns __fp16x2)
__device__ __forceinline__ f16x2 pkrtz(float a, float b) {
    auto p = __builtin_amdgcn_cvt_pkrtz(a, b);
    f16x2 r; __builtin_memcpy(&r, &p, 4); return r;
}
// TBAA-safe LDS loads: memcpy carries char aliasing -> may-alias the _Float16
// hist stores -> compiler preserves program order (R14's corruption was the
// *(unsigned*)/uint4 punned loads being reorderable around _Float16 stores
// once the wbar fences were removed).
__device__ __forceinline__ uint4 ld16(const void* p) {
    uint4 r; __builtin_memcpy(&r, p, 16); return r;
}
__device__ __forceinline__ unsigned ld4(const void* p) {
    unsigned r; __builtin_memcpy(&r, p, 4); return r;
}
__device__ __forceinline__ void wbar() { __builtin_amdgcn_wave_barrier(); }

// R15: R14 structure (gate-ordered dots + full filler distribution) with all
// type-punned LDS reads hardened via memcpy (see above). Schedule:
//   s0-4: MFMA tile t (+D-write t-1);  s1: xg hi-half prefetch;
//   s3/s7: output store chunks c0/c1;  s5: D-write t4;  s6: A-loads g+2;
//   bottom: chunk c2 + h carry + wbar.
// Gate-ordered dots: r-gate's 12 fdot2 first so sigm(r)'s trans chain
// overlaps z/n dot issue; per-accumulator op order unchanged (bit-identical).
template <bool L0, bool LAST>
__global__ __launch_bounds__(256) void gru_mfma(
    const void* __restrict__ in_,        // L0: x [B][T][32] f32; else region0 (region1 at +DSTRIDE)
    const float* __restrict__ fmean, const float* __restrict__ fstd,
    const float* __restrict__ wih_g, const float* __restrict__ whh_g,
    const float* __restrict__ bih_g, const float* __restrict__ bhh_g,
    unsigned short* __restrict__ outbuf, float* __restrict__ lastbuf)
{
    constexpr int KIN = L0 ? 32 : 46;
    constexpr int KF  = L0 ? 1 : 2;
    constexpr int DSTR = 20;             // D-tile row stride (f32), 80B

    // [tile t<5][kslot<8][lane m<16][8 halves] staging for B-frags
    __shared__ __align__(16) _Float16  wih_lds[5 * 8 * 16 * 8];
    __shared__ __align__(16) _Float16  whh_h[80 * 24];       // W_hh f16
    __shared__ __align__(16) float     xg_s[4][2][80 * DSTR]; // per-wave D dbuf
    __shared__ __align__(16) _Float16  hist_h[4 * 9 * 2 * 32];  // h history f16
    __shared__ float bih_s[80], bhh_s[80];
    __shared__ __align__(16) float an_s[32], cn_s[32];

    const int tid = threadIdx.x, wv = tid >> 6, lane = tid & 63;
    const int bl = lane >> 5, u = lane & 31;
    const int m  = lane & 15, kg = lane >> 4;             // MFMA lane coords
    const int dir = blockIdx.y;
    const int bg  = blockIdx.x * 8 + wv * 2 + bl;

    const float* wih_d = wih_g + dir * 69 * KIN;
    const float* whh_d = whh_g + dir * 69 * 23;

    // ---- stage W_ih frags [t][kslot][m][8], col-remapped, zero-padded ----
    for (int idx = tid; idx < 5120; idx += 256) {
        int t = idx >> 10, r = idx & 1023;
        int kslot = r >> 7, mm = (r >> 3) & 15, j = r & 7;
        int row = t * 16 + mm, k = kslot * 8 + j;
        float v = 0.f;
        if (row < 69) {
            if constexpr (L0) {
                if (k < 32) v = wih_d[row * 32 + k];
            } else {
                if (k < 23) v = wih_d[row * 46 + k];                      // fwd
                else if (k >= 24 && k < 47) v = wih_d[row * 46 + k - 1];  // bwd
            }
        }
        wih_lds[idx] = (_Float16)v;
    }
    for (int idx = tid; idx < 80 * 24; idx += 256) {
        int j = idx / 24, k = idx - j * 24;
        whh_h[idx] = (j < 69 && k < 23) ? (_Float16)whh_d[j * 23 + k]
                                        : (_Float16)0.f;
    }
    for (int idx = tid; idx < 80; idx += 256) {
        bih_s[idx] = (idx < 69) ? bih_g[dir * 69 + idx] : 0.f;
        bhh_s[idx] = (idx < 69) ? bhh_g[dir * 69 + idx] : 0.f;
    }
    for (int idx = tid; idx < 4 * 9 * 2 * 32; idx += 256)
        hist_h[idx] = (_Float16)0.f;
    if (L0 && tid < 32) {
        float sd = fstd[tid];
        float sa = (sd == 0.f) ? 1.f : sd;        // std==0 -> 1
        float a  = (sa == 1.f) ? 0.f : 1.f / sa;  // adjusted std==1 -> zero
        an_s[tid] = a;
        cn_s[tid] = -fmean[tid] * a;
    }
    __syncthreads();   // only block-wide barrier

    // ---- per-lane W_hh rows (u, 23+u, 46+u) as f16 pairs -> 36 VGPRs ----
    unsigned wrp[3][12];
    float bh2;
    #pragma unroll
    for (int r = 0; r < 3; ++r) {
        int row = r * 23 + u;   // <= 77 < 80
        #pragma unroll
        for (int k = 0; k < 12; ++k)
            wrp[r][k] = ld4(&whh_h[row * 24 + 2 * k]);
    }
    bh2 = bhh_s[46 + u];   // n-row b_hh stays inside r*(...)
    // D-tile bias: b_ih (+ b_hh for r/z rows, which add outside the r gate)
    float bi5[5];
    #pragma unroll
    for (int t = 0; t < 5; ++t) {
        int n = t * 16 + m;
        bi5[t] = bih_s[n] + (n < 46 ? bhh_s[n] : 0.f);
    }

    // ---- B-fragments register-resident ----
    const f16x8* bfrag = (const f16x8*)wih_lds;   // [t*8+kslot][m]
    f16x8 bfr[5][KF];
    #pragma unroll
    for (int t = 0; t < 5; ++t)
        #pragma unroll
        for (int kf = 0; kf < KF; ++kf)
            bfr[t][kf] = bfrag[(t * 8 + kf * 4 + kg) * 16 + m];

    float an8[L0 ? 8 : 1], cn8[L0 ? 8 : 1];
    if constexpr (L0) {
        #pragma unroll
        for (int j = 0; j < 8; ++j) {
            an8[j] = an_s[kg * 8 + j];
            cn8[j] = cn_s[kg * 8 + j];
        }
    }

    float* db0 = &xg_s[wv][0][0];
    float* db1 = &xg_s[wv][1][0];
    _Float16* hw = &hist_h[wv * 9 * 2 * 32];
    const int ngroups = (LAST && dir == 1) ? 1 : 64;
    float hold = 0.f;

    // ---- store-phase lane constants (hoisted) ----
    int sarr[3], cparr[3], ldsoff[3];
    {
        int idx = lane & 31;
        #pragma unroll
        for (int c = 0; c < 3; ++c) {
            int p = idx + 32 * c;             // 0..95
            sarr[c]  = p / 12;
            cparr[c] = p - 12 * sarr[c];
            ldsoff[c] = ((sarr[c] + 1) * 2 + bl) * 32 + 2 * cparr[c];
        }
    }
    unsigned short* dstbase = nullptr;
    if constexpr (!LAST)
        dstbase = outbuf + dir * DSTRIDE + (size_t)bg * TT * 24;

    // A-row coords: m = bl_a*8 + tl
    const int bl_a = m >> 3, tl = m & 7;
    const int b_a  = blockIdx.x * 8 + wv * 2 + bl_a;

    const unsigned short* r0 = (const unsigned short*)in_;
    const unsigned short* r1 = r0 + DSTRIDE;

    float4 xraw0, xraw1;                 // L0 raw x
    f16x8 a0r, a1r;                      // !L0 f16 frags

    // ---- load raw A data for group 0 ----
    {
        const int tg_a = dir ? (511 - tl) : tl;
        if constexpr (L0) {
            const float* xr = (const float*)in_ +
                              ((size_t)b_a * TT + tg_a) * 32 + kg * 8;
            xraw0 = *(const float4*)xr;
            xraw1 = *(const float4*)(xr + 4);
        } else {
            size_t rowoff = ((size_t)b_a * TT + tg_a) * 24;
            const unsigned short* p0 =
                (kg < 3) ? (r0 + rowoff + 8 * kg) : (r1 + rowoff);
            const unsigned short* p1 =
                (kg == 0) ? (r1 + rowoff + 8) : (r1 + rowoff + 16);
            __builtin_memcpy(&a0r, p0, 16);
            __builtin_memcpy(&a1r, p1, 16);
        }
    }

    // ---- prologue: MFMA for group 0 -> db0 (monolithic, once) ----
    {
        f32x4 acc[5];
        #pragma unroll
        for (int t = 0; t < 5; ++t)
            acc[t] = (f32x4){bi5[t], bi5[t], bi5[t], bi5[t]};
        if constexpr (L0) {
            float xv[8] = {xraw0.x, xraw0.y, xraw0.z, xraw0.w,
                           xraw1.x, xraw1.y, xraw1.z, xraw1.w};
            f16x8 afr;
            #pragma unroll
            for (int j = 0; j < 4; ++j) {
                f16x2 p = pkrtz(xv[2 * j] * an8[2 * j] + cn8[2 * j],
                                xv[2 * j + 1] * an8[2 * j + 1] + cn8[2 * j + 1]);
                afr[2 * j]     = p[0];
                afr[2 * j + 1] = p[1];
            }
            #pragma unroll
            for (int t = 0; t < 5; ++t)
                acc[t] = __builtin_amdgcn_mfma_f32_16x16x32_f16(afr, bfr[t][0],
                                                                acc[t], 0, 0, 0);
        } else {
            f16x8 zz = {};
            f16x8 a0u = a0r;
            f16x8 a1u = (kg >= 2) ? zz : a1r;
            #pragma unroll
            for (int t = 0; t < 5; ++t) {
                acc[t] = __builtin_amdgcn_mfma_f32_16x16x32_f16(a0u, bfr[t][0],
                                                                acc[t], 0, 0, 0);
                acc[t] = __builtin_amdgcn_mfma_f32_16x16x32_f16(a1u, bfr[t][1],
                                                                acc[t], 0, 0, 0);
            }
        }
        #pragma unroll
        for (int t = 0; t < 5; ++t)
            *(f32x4*)&db0[(t * 16 + m) * DSTR + kg * 4] = acc[t];
    }
    // ---- load raw A data for group 1 ----
    if (1 < ngroups) {
        const int tg_a = dir ? (511 - (8 + tl)) : (8 + tl);
        if constexpr (L0) {
            const float* xr = (const float*)in_ +
                              ((size_t)b_a * TT + tg_a) * 32 + kg * 8;
            xraw0 = *(const float4*)xr;
            xraw1 = *(const float4*)(xr + 4);
        } else {
            size_t rowoff = ((size_t)b_a * TT + tg_a) * 24;
            const unsigned short* p0 =
                (kg < 3) ? (r0 + rowoff + 8 * kg) : (r1 + rowoff);
            const unsigned short* p1 =
                (kg == 0) ? (r1 + rowoff + 8) : (r1 + rowoff + 16);
            __builtin_memcpy(&a0r, p0, 16);
            __builtin_memcpy(&a1r, p1, 16);
        }
    }

    int cur = 0;
    for (int g = 0; g < ngroups; ++g) {
        float* Dc = cur ? db1 : db0;
        float* Dn = cur ? db0 : db1;
        wbar();   // D(cur) writes precede in program order (in-order DS)

        // lo-half xg prefetch (steps 0-3); hi-half fetched in step-1 filler
        f32x4 xlo[3], xhi[3];
        #pragma unroll
        for (int c = 0; c < 3; ++c)
            xlo[c] = *(const f32x4*)&Dc[(c * 23 + u) * DSTR + bl * 8];

        const bool domfma = (g + 1 < ngroups);
        const bool doload = (g + 2 < ngroups);
        f32x4 acc[5];
        f16x8 afr;

        // ---- 8 scan steps with group work distributed into read-wait slots --
        #pragma unroll
        for (int s8 = 0; s8 < 8; ++s8) {
            const _Float16* hr = &hw[(s8 * 2 + bl) * 32];   // prev h (f16)
            uint4 hq0 = ld16(hr);          // f16 0..7
            uint4 hq1 = ld16(hr + 8);      // f16 8..15
            uint4 hq2 = ld16(hr + 16);     // f16 16..23

            // ---- filler: independent work under hist-read latency ----
            if (s8 == 1) {
                #pragma unroll
                for (int c = 0; c < 3; ++c)
                    xhi[c] = *(const f32x4*)&Dc[(c * 23 + u) * DSTR + bl * 8 + 4];
            }
            if (s8 <= 4) {
                if (domfma) {
                    if constexpr (L0) {
                        if (s8 == 0) {
                            float xv[8] = {xraw0.x, xraw0.y, xraw0.z, xraw0.w,
                                           xraw1.x, xraw1.y, xraw1.z, xraw1.w};
                            #pragma unroll
                            for (int j = 0; j < 4; ++j) {
                                f16x2 p = pkrtz(
                                    xv[2 * j] * an8[2 * j] + cn8[2 * j],
                                    xv[2 * j + 1] * an8[2 * j + 1] + cn8[2 * j + 1]);
                                afr[2 * j]     = p[0];
                                afr[2 * j + 1] = p[1];
                            }
                        }
                        acc[s8] = (f32x4){bi5[s8], bi5[s8], bi5[s8], bi5[s8]};
                        acc[s8] = __builtin_amdgcn_mfma_f32_16x16x32_f16(
                            afr, bfr[s8][0], acc[s8], 0, 0, 0);
                    } else {
                        if (s8 == 0) {
                            f16x8 zz = {};
                            if (kg >= 2) a1r = zz;   // reloaded at s6 anyway
                        }
                        acc[s8] = (f32x4){bi5[s8], bi5[s8], bi5[s8], bi5[s8]};
                        acc[s8] = __builtin_amdgcn_mfma_f32_16x16x32_f16(
                            a0r, bfr[s8][0], acc[s8], 0, 0, 0);
                        acc[s8] = __builtin_amdgcn_mfma_f32_16x16x32_f16(
                            a1r, bfr[s8][1], acc[s8], 0, 0, 0);
                    }
                    if (s8 >= 1)
                        *(f32x4*)&Dn[((s8 - 1) * 16 + m) * DSTR + kg * 4] =
                            acc[s8 - 1];
                }
            } else if (s8 == 5) {
                if (domfma)
                    *(f32x4*)&Dn[(4 * 16 + m) * DSTR + kg * 4] = acc[4];
            } else if (s8 == 6) {
                if (doload) {
                    const int tg_n = dir ? (511 - ((g + 2) * 8 + tl))
                                         : ((g + 2) * 8 + tl);
                    if constexpr (L0) {
                        const float* xr = (const float*)in_ +
                                          ((size_t)b_a * TT + tg_n) * 32 + kg * 8;
                        xraw0 = *(const float4*)xr;
                        xraw1 = *(const float4*)(xr + 4);
                    } else {
                        size_t rowoff = ((size_t)b_a * TT + tg_n) * 24;
                        const unsigned short* p0 =
                            (kg < 3) ? (r0 + rowoff + 8 * kg) : (r1 + rowoff);
                        const unsigned short* p1 =
                            (kg == 0) ? (r1 + rowoff + 8) : (r1 + rowoff + 16);
                        __builtin_memcpy(&a0r, p0, 16);
                        __builtin_memcpy(&a1r, p1, 16);
                    }
                }
            }
            // inline store chunks: c0 at s3 (hist rows 1-3, written by s2);
            // c1 at s7 (rows 3-6, written by s5). ld4 = memcpy -> ordered
            // w.r.t. the _Float16 hist stores (may-alias).
            if constexpr (!LAST) {
                if (s8 == 3 || s8 == 7) {
                    const int c = (s8 == 3) ? 0 : 1;
                    unsigned w = ld4(&hw[ldsoff[c]]);
                    if (cparr[c] == 11) w &= 0xFFFFu;   // col 23 := 0
                    int tg = dir ? (511 - (g * 8 + sarr[c]))
                                 : (g * 8 + sarr[c]);
                    *(unsigned*)(dstbase + (size_t)tg * 24 + 2 * cparr[c]) = w;
                }
            }

            // ---- gate-ordered dots: r first, trans overlaps z/n dot issue ----
            unsigned hwd[12] = {hq0.x, hq0.y, hq0.z, hq0.w,
                                hq1.x, hq1.y, hq1.z, hq1.w,
                                hq2.x, hq2.y, hq2.z, hq2.w};
            const float xg0 = (s8 < 4) ? xlo[0][s8] : xhi[0][s8 - 4];
            const float xg1 = (s8 < 4) ? xlo[1][s8] : xhi[1][s8 - 4];
            const float xg2 = (s8 < 4) ? xlo[2][s8] : xhi[2][s8 - 4];

            float a0a = xg0, a0b = 0.f;
            #pragma unroll
            for (int k = 0; k < 6; ++k)
                a0a = __builtin_amdgcn_fdot2(asf16x2(wrp[0][k]), asf16x2(hwd[k]),
                                             a0a, false);
            #pragma unroll
            for (int k = 6; k < 12; ++k)
                a0b = __builtin_amdgcn_fdot2(asf16x2(wrp[0][k]), asf16x2(hwd[k]),
                                             a0b, false);
            float r_ = sigm(a0a + a0b);            // trans chain starts early

            float a1a = xg1, a1b = 0.f;
            #pragma unroll
            for (int k = 0; k < 6; ++k)
                a1a = __builtin_amdgcn_fdot2(asf16x2(wrp[1][k]), asf16x2(hwd[k]),
                                             a1a, false);
            #pragma unroll
            for (int k = 6; k < 12; ++k)
                a1b = __builtin_amdgcn_fdot2(asf16x2(wrp[1][k]), asf16x2(hwd[k]),
                                             a1b, false);
            float z_ = sigm(a1a + a1b);

            float a2a = bh2, a2b = 0.f;
            #pragma unroll
            for (int k = 0; k < 6; ++k)
                a2a = __builtin_amdgcn_fdot2(asf16x2(wrp[2][k]), asf16x2(hwd[k]),
                                             a2a, false);
            #pragma unroll
            for (int k = 6; k < 12; ++k)
                a2b = __builtin_amdgcn_fdot2(asf16x2(wrp[2][k]), asf16x2(hwd[k]),
                                             a2b, false);
            float n_ = tanh_(__builtin_fmaf(r_, a2a + a2b, xg2));

            float hnew = n_ + z_ * (hold - n_);
            hold = hnew;
            if constexpr (LAST) {
                int tg = dir ? (511 - (g * 8 + s8)) : (g * 8 + s8);
                if (u < 23 && tg == TT - 1)
                    lastbuf[bg * 48 + dir * 23 + u] = hnew;
            }
            hw[((s8 + 1) * 2 + bl) * 32 + u] = (_Float16)hnew;  // pads in 24..31
        }

        // ---- group bottom: store chunk c2 (rows 6-8 incl. step-7 write) ----
        if constexpr (!LAST) {
            unsigned w = ld4(&hw[ldsoff[2]]);
            if (cparr[2] == 11) w &= 0xFFFFu;   // col 23 := 0
            int tg = dir ? (511 - (g * 8 + sarr[2])) : (g * 8 + sarr[2]);
            *(unsigned*)(dstbase + (size_t)tg * 24 + 2 * cparr[2]) = w;
        }
        // carry h into row 0 for next group (disjoint from store-phase rows)
        hw[bl * 32 + u] = (_Float16)hold;
        wbar();
        cur ^= 1;
    }
}

__global__ __launch_bounds__(256) void fc_kernel(
    const float* __restrict__ last, const float* __restrict__ fcw,
    const float* __restrict__ fcb, const float* __restrict__ ostd,
    const float* __restrict__ omean, float* __restrict__ out)
{
    int idx = blockIdx.x * 256 + threadIdx.x;
    if (idx >= BB * NOUT) return;
    int b = idx >> 3, o = idx & 7;
    float acc = fcb[o];
    const float* lr = last + b * 48;
    const float* wr = fcw + o * 46;
    #pragma unroll
    for (int i = 0; i < 46; i++) acc += lr[i] * wr[i];
    out[idx] = acc * ostd[o] + omean[o];
}

extern "C" void kernel_launch(void* const* d_in, const int* in_sizes, int n_in,
                              void* d_out, int out_size, void* d_ws,
                              size_t ws_size, hipStream_t stream)
{
    const float* x     = (const float*)d_in[0];
    const float* fmean = (const float*)d_in[1];
    const float* fstd  = (const float*)d_in[2];
    const float* omean = (const float*)d_in[3];
    const float* ostd  = (const float*)d_in[4];
    const float* wih0  = (const float*)d_in[5];
    const float* whh0  = (const float*)d_in[6];
    const float* bih0  = (const float*)d_in[7];
    const float* bhh0  = (const float*)d_in[8];
    const float* wihr  = (const float*)d_in[9];
    const float* whhr  = (const float*)d_in[10];
    const float* bihr  = (const float*)d_in[11];
    const float* bhhr  = (const float*)d_in[12];
    const float* fcw   = (const float*)d_in[13];
    const float* fcb   = (const float*)d_in[14];

    char* ws = (char*)d_ws;
    const size_t bufBytes = 2 * DSTRIDE * sizeof(unsigned short);  // 96 MiB
    unsigned short* buf0 = (unsigned short*)ws;
    unsigned short* buf1 = (unsigned short*)(ws + bufBytes);
    float* lastb         = (float*)(ws + 2 * bufBytes);

    dim3 grid(BB / 8, 2);

    gru_mfma<true, false><<<grid, 256, 0, stream>>>(
        x, fmean, fstd, wih0, whh0, bih0, bhh0, buf0, nullptr);
    gru_mfma<false, false><<<grid, 256, 0, stream>>>(
        buf0, nullptr, nullptr, wihr + 0 * 2 * 69 * 46, whhr + 0 * 2 * 69 * 23,
        bihr + 0 * 2 * 69, bhhr + 0 * 2 * 69, buf1, nullptr);
    gru_mfma<false, true><<<grid, 256, 0, stream>>>(
        buf1, nullptr, nullptr, wihr + 1 * 2 * 69 * 46, whhr + 1 * 2 * 69 * 23,
        bihr + 1 * 2 * 69, bhhr + 1 * 2 * 69, nullptr, lastb);
    fc_kernel<<<(BB * NOUT + 255) / 256, 256, 0, stream>>>(lastb, fcw, fcb, ostd,
                                                           omean, (float*)d_out);
}

// Round 8
// 620.875 us; speedup vs baseline: 1.0158x; 1.0158x over previous
//
#include <hip/hip_runtime.h>
#include <hip/hip_bf16.h>

constexpr int TT = 512, BB = 2048, NOUT = 8;
constexpr size_t DSTRIDE = (size_t)BB * TT * 24;   // f16 elems per dir region

typedef __attribute__((ext_vector_type(8))) _Float16 f16x8;
typedef __attribute__((ext_vector_type(4))) float f32x4;
typedef __attribute__((ext_vector_type(2))) _Float16 f16x2;

// fast device math: v_exp_f32 / v_rcp_f32 (1-ulp approx, no div sequence)
__device__ __forceinline__ float sigm(float x) {
    float e = __builtin_amdgcn_exp2f(x * -1.4426950408889634f);
    return __builtin_amdgcn_rcpf(1.f + e);
}
__device__ __forceinline__ float tanh_(float x) {
    float e = __builtin_amdgcn_exp2f(x * 2.8853900817779268f);
    return __builtin_fmaf(-2.f, __builtin_amdgcn_rcpf(e + 1.f), 1.f);
}
__device__ __forceinline__ f16x2 asf16x2(unsigned v) {
    f16x2 r; __builtin_memcpy(&r, &v, 4); return r;
}
// v_cvt_pkrtz_f16_f32 with a bit-cast to our f16x2 (builtin returns __fp16x2)
__device__ __forceinline__ f16x2 pkrtz(float a, float b) {
    auto p = __builtin_amdgcn_cvt_pkrtz(a, b);
    f16x2 r; __builtin_memcpy(&r, &p, 4); return r;
}
// TBAA-safe LDS loads: memcpy carries char aliasing -> may-alias the _Float16
// hist stores -> compiler preserves program order.
__device__ __forceinline__ uint4 ld16(const void* p) {
    uint4 r; __builtin_memcpy(&r, p, 16); return r;
}
__device__ __forceinline__ unsigned ld4(const void* p) {
    unsigned r; __builtin_memcpy(&r, p, 4); return r;
}
__device__ __forceinline__ void wbar() { __builtin_amdgcn_wave_barrier(); }

// R16: revert to the R13 schedule (best measured: 200.6us/dispatch) with
// R15's memcpy hardening, plus wave DE-PHASING. Evidence: R15's gate-ordered
// dots + inline stores regressed (204.7); R13's schedule is the local opt.
// New lever: the two co-resident waves per SIMD run identical code in
// near-lockstep -> their dense-issue (fdot2) and stall (trans+DS) phases are
// correlated; VALUBusy 65% with ~35% both-stalled time. No block-wide
// barriers exist in the loop, so a ONE-TIME ~half-step sleep for one of the
// two co-resident blocks de-phases them permanently: A's dot-issue fills B's
// stall. XOR of blockIdx parities covers both plausible block->CU pairings.
template <bool L0, bool LAST>
__global__ __launch_bounds__(256) void gru_mfma(
    const void* __restrict__ in_,        // L0: x [B][T][32] f32; else region0 (region1 at +DSTRIDE)
    const float* __restrict__ fmean, const float* __restrict__ fstd,
    const float* __restrict__ wih_g, const float* __restrict__ whh_g,
    const float* __restrict__ bih_g, const float* __restrict__ bhh_g,
    unsigned short* __restrict__ outbuf, float* __restrict__ lastbuf)
{
    constexpr int KIN = L0 ? 32 : 46;
    constexpr int KF  = L0 ? 1 : 2;
    constexpr int DSTR = 20;             // D-tile row stride (f32), 80B

    // [tile t<5][kslot<8][lane m<16][8 halves] staging for B-frags
    __shared__ __align__(16) _Float16  wih_lds[5 * 8 * 16 * 8];
    __shared__ __align__(16) _Float16  whh_h[80 * 24];       // W_hh f16
    __shared__ __align__(16) float     xg_s[4][2][80 * DSTR]; // per-wave D dbuf
    __shared__ __align__(16) _Float16  hist_h[4 * 9 * 2 * 32];  // h history f16
    __shared__ float bih_s[80], bhh_s[80];
    __shared__ __align__(16) float an_s[32], cn_s[32];

    const int tid = threadIdx.x, wv = tid >> 6, lane = tid & 63;
    const int bl = lane >> 5, u = lane & 31;
    const int m  = lane & 15, kg = lane >> 4;             // MFMA lane coords
    const int dir = blockIdx.y;
    const int bg  = blockIdx.x * 8 + wv * 2 + bl;

    const float* wih_d = wih_g + dir * 69 * KIN;
    const float* whh_d = whh_g + dir * 69 * 23;

    // ---- stage W_ih frags [t][kslot][m][8], col-remapped, zero-padded ----
    for (int idx = tid; idx < 5120; idx += 256) {
        int t = idx >> 10, r = idx & 1023;
        int kslot = r >> 7, mm = (r >> 3) & 15, j = r & 7;
        int row = t * 16 + mm, k = kslot * 8 + j;
        float v = 0.f;
        if (row < 69) {
            if constexpr (L0) {
                if (k < 32) v = wih_d[row * 32 + k];
            } else {
                if (k < 23) v = wih_d[row * 46 + k];                      // fwd
                else if (k >= 24 && k < 47) v = wih_d[row * 46 + k - 1];  // bwd
            }
        }
        wih_lds[idx] = (_Float16)v;
    }
    for (int idx = tid; idx < 80 * 24; idx += 256) {
        int j = idx / 24, k = idx - j * 24;
        whh_h[idx] = (j < 69 && k < 23) ? (_Float16)whh_d[j * 23 + k]
                                        : (_Float16)0.f;
    }
    for (int idx = tid; idx < 80; idx += 256) {
        bih_s[idx] = (idx < 69) ? bih_g[dir * 69 + idx] : 0.f;
        bhh_s[idx] = (idx < 69) ? bhh_g[dir * 69 + idx] : 0.f;
    }
    for (int idx = tid; idx < 4 * 9 * 2 * 32; idx += 256)
        hist_h[idx] = (_Float16)0.f;
    if (L0 && tid < 32) {
        float sd = fstd[tid];
        float sa = (sd == 0.f) ? 1.f : sd;        // std==0 -> 1
        float a  = (sa == 1.f) ? 0.f : 1.f / sa;  // adjusted std==1 -> zero
        an_s[tid] = a;
        cn_s[tid] = -fmean[tid] * a;
    }
    __syncthreads();   // only block-wide barrier

    // ---- per-lane W_hh rows (u, 23+u, 46+u) as f16 pairs -> 36 VGPRs ----
    unsigned wrp[3][12];
    float bh2;
    #pragma unroll
    for (int r = 0; r < 3; ++r) {
        int row = r * 23 + u;   // <= 77 < 80
        #pragma unroll
        for (int k = 0; k < 12; ++k)
            wrp[r][k] = ld4(&whh_h[row * 24 + 2 * k]);
    }
    bh2 = bhh_s[46 + u];   // n-row b_hh stays inside r*(...)
    // D-tile bias: b_ih (+ b_hh for r/z rows, which add outside the r gate)
    float bi5[5];
    #pragma unroll
    for (int t = 0; t < 5; ++t) {
        int n = t * 16 + m;
        bi5[t] = bih_s[n] + (n < 46 ? bhh_s[n] : 0.f);
    }

    // ---- B-fragments register-resident ----
    const f16x8* bfrag = (const f16x8*)wih_lds;   // [t*8+kslot][m]
    f16x8 bfr[5][KF];
    #pragma unroll
    for (int t = 0; t < 5; ++t)
        #pragma unroll
        for (int kf = 0; kf < KF; ++kf)
            bfr[t][kf] = bfrag[(t * 8 + kf * 4 + kg) * 16 + m];

    float an8[L0 ? 8 : 1], cn8[L0 ? 8 : 1];
    if constexpr (L0) {
        #pragma unroll
        for (int j = 0; j < 8; ++j) {
            an8[j] = an_s[kg * 8 + j];
            cn8[j] = cn_s[kg * 8 + j];
        }
    }

    float* db0 = &xg_s[wv][0][0];
    float* db1 = &xg_s[wv][1][0];
    _Float16* hw = &hist_h[wv * 9 * 2 * 32];
    const int ngroups = (LAST && dir == 1) ? 1 : 64;
    float hold = 0.f;

    // ---- store-phase lane constants (hoisted) ----
    int sarr[3], cparr[3], ldsoff[3];
    {
        int idx = lane & 31;
        #pragma unroll
        for (int c = 0; c < 3; ++c) {
            int p = idx + 32 * c;             // 0..95
            sarr[c]  = p / 12;
            cparr[c] = p - 12 * sarr[c];
            ldsoff[c] = ((sarr[c] + 1) * 2 + bl) * 32 + 2 * cparr[c];
        }
    }
    unsigned short* dstbase = nullptr;
    if constexpr (!LAST)
        dstbase = outbuf + dir * DSTRIDE + (size_t)bg * TT * 24;

    // A-row coords: m = bl_a*8 + tl
    const int bl_a = m >> 3, tl = m & 7;
    const int b_a  = blockIdx.x * 8 + wv * 2 + bl_a;

    const unsigned short* r0 = (const unsigned short*)in_;
    const unsigned short* r1 = r0 + DSTRIDE;

    float4 xraw0, xraw1;                 // L0 raw x
    f16x8 a0r, a1r;                      // !L0 f16 frags

    // ---- load raw A data for group 0 ----
    {
        const int tg_a = dir ? (511 - tl) : tl;
        if constexpr (L0) {
            const float* xr = (const float*)in_ +
                              ((size_t)b_a * TT + tg_a) * 32 + kg * 8;
            xraw0 = *(const float4*)xr;
            xraw1 = *(const float4*)(xr + 4);
        } else {
            size_t rowoff = ((size_t)b_a * TT + tg_a) * 24;
            const unsigned short* p0 =
                (kg < 3) ? (r0 + rowoff + 8 * kg) : (r1 + rowoff);
            const unsigned short* p1 =
                (kg == 0) ? (r1 + rowoff + 8) : (r1 + rowoff + 16);
            __builtin_memcpy(&a0r, p0, 16);
            __builtin_memcpy(&a1r, p1, 16);
        }
    }

    // ---- prologue: MFMA for group 0 -> db0 (monolithic, once) ----
    {
        f32x4 acc[5];
        #pragma unroll
        for (int t = 0; t < 5; ++t)
            acc[t] = (f32x4){bi5[t], bi5[t], bi5[t], bi5[t]};
        if constexpr (L0) {
            float xv[8] = {xraw0.x, xraw0.y, xraw0.z, xraw0.w,
                           xraw1.x, xraw1.y, xraw1.z, xraw1.w};
            f16x8 afr;
            #pragma unroll
            for (int j = 0; j < 4; ++j) {
                f16x2 p = pkrtz(xv[2 * j] * an8[2 * j] + cn8[2 * j],
                                xv[2 * j + 1] * an8[2 * j + 1] + cn8[2 * j + 1]);
                afr[2 * j]     = p[0];
                afr[2 * j + 1] = p[1];
            }
            #pragma unroll
            for (int t = 0; t < 5; ++t)
                acc[t] = __builtin_amdgcn_mfma_f32_16x16x32_f16(afr, bfr[t][0],
                                                                acc[t], 0, 0, 0);
        } else {
            f16x8 zz = {};
            f16x8 a0u = a0r;
            f16x8 a1u = (kg >= 2) ? zz : a1r;
            #pragma unroll
            for (int t = 0; t < 5; ++t) {
                acc[t] = __builtin_amdgcn_mfma_f32_16x16x32_f16(a0u, bfr[t][0],
                                                                acc[t], 0, 0, 0);
                acc[t] = __builtin_amdgcn_mfma_f32_16x16x32_f16(a1u, bfr[t][1],
                                                                acc[t], 0, 0, 0);
            }
        }
        #pragma unroll
        for (int t = 0; t < 5; ++t)
            *(f32x4*)&db0[(t * 16 + m) * DSTR + kg * 4] = acc[t];
    }
    // ---- load raw A data for group 1 ----
    if (1 < ngroups) {
        const int tg_a = dir ? (511 - (8 + tl)) : (8 + tl);
        if constexpr (L0) {
            const float* xr = (const float*)in_ +
                              ((size_t)b_a * TT + tg_a) * 32 + kg * 8;
            xraw0 = *(const float4*)xr;
            xraw1 = *(const float4*)(xr + 4);
        } else {
            size_t rowoff = ((size_t)b_a * TT + tg_a) * 24;
            const unsigned short* p0 =
                (kg < 3) ? (r0 + rowoff + 8 * kg) : (r1 + rowoff);
            const unsigned short* p1 =
                (kg == 0) ? (r1 + rowoff + 8) : (r1 + rowoff + 16);
            __builtin_memcpy(&a0r, p0, 16);
            __builtin_memcpy(&a1r, p1, 16);
        }
    }

    // ---- de-phase the two co-resident blocks' waves (one-time, ~512cy) ----
    if ((blockIdx.x ^ blockIdx.y) & 1)
        __builtin_amdgcn_s_sleep(8);

    int cur = 0;
    for (int g = 0; g < ngroups; ++g) {
        float* Dc = cur ? db1 : db0;
        float* Dn = cur ? db0 : db1;
        wbar();   // D(cur) writes precede in program order (in-order DS)

        // ---- prefetch this group's xg: 2x b128 per gate row (col-major D) --
        float xgr[8][3];
        #pragma unroll
        for (int c = 0; c < 3; ++c) {
            const f32x4 lo = *(const f32x4*)&Dc[(c * 23 + u) * DSTR + bl * 8];
            const f32x4 hi = *(const f32x4*)&Dc[(c * 23 + u) * DSTR + bl * 8 + 4];
            #pragma unroll
            for (int s = 0; s < 8; ++s)
                xgr[s][c] = (s < 4) ? lo[s] : hi[s - 4];
        }

        const bool domfma = (g + 1 < ngroups);
        const bool doload = (g + 2 < ngroups);
        f32x4 acc[5];
        f16x8 afr;

        // ---- 8 scan steps with next-group work interleaved (R13 schedule) --
        #pragma unroll
        for (int s8 = 0; s8 < 8; ++s8) {
            const _Float16* hr = &hw[(s8 * 2 + bl) * 32];   // prev h (f16)
            uint4 hq0 = ld16(hr);          // f16 0..7
            uint4 hq1 = ld16(hr + 8);      // f16 8..15
            uint4 hq2 = ld16(hr + 16);     // f16 16..23

            // ---- filler: independent work under hist-read latency ----
            if (s8 <= 4) {
                if (domfma) {
                    if constexpr (L0) {
                        if (s8 == 0) {
                            float xv[8] = {xraw0.x, xraw0.y, xraw0.z, xraw0.w,
                                           xraw1.x, xraw1.y, xraw1.z, xraw1.w};
                            #pragma unroll
                            for (int j = 0; j < 4; ++j) {
                                f16x2 p = pkrtz(
                                    xv[2 * j] * an8[2 * j] + cn8[2 * j],
                                    xv[2 * j + 1] * an8[2 * j + 1] + cn8[2 * j + 1]);
                                afr[2 * j]     = p[0];
                                afr[2 * j + 1] = p[1];
                            }
                        }
                        acc[s8] = (f32x4){bi5[s8], bi5[s8], bi5[s8], bi5[s8]};
                        acc[s8] = __builtin_amdgcn_mfma_f32_16x16x32_f16(
                            afr, bfr[s8][0], acc[s8], 0, 0, 0);
                    } else {
                        if (s8 == 0) {
                            f16x8 zz = {};
                            if (kg >= 2) a1r = zz;   // reloaded at s6 anyway
                        }
                        acc[s8] = (f32x4){bi5[s8], bi5[s8], bi5[s8], bi5[s8]};
                        acc[s8] = __builtin_amdgcn_mfma_f32_16x16x32_f16(
                            a0r, bfr[s8][0], acc[s8], 0, 0, 0);
                        acc[s8] = __builtin_amdgcn_mfma_f32_16x16x32_f16(
                            a1r, bfr[s8][1], acc[s8], 0, 0, 0);
                    }
                    if (s8 >= 1)
                        *(f32x4*)&Dn[((s8 - 1) * 16 + m) * DSTR + kg * 4] =
                            acc[s8 - 1];
                }
            } else if (s8 == 5) {
                if (domfma)
                    *(f32x4*)&Dn[(4 * 16 + m) * DSTR + kg * 4] = acc[4];
            } else if (s8 == 6) {
                if (doload) {
                    const int tg_n = dir ? (511 - ((g + 2) * 8 + tl))
                                         : ((g + 2) * 8 + tl);
                    if constexpr (L0) {
                        const float* xr = (const float*)in_ +
                                          ((size_t)b_a * TT + tg_n) * 32 + kg * 8;
                        xraw0 = *(const float4*)xr;
                        xraw1 = *(const float4*)(xr + 4);
                    } else {
                        size_t rowoff = ((size_t)b_a * TT + tg_n) * 24;
                        const unsigned short* p0 =
                            (kg < 3) ? (r0 + rowoff + 8 * kg) : (r1 + rowoff);
                        const unsigned short* p1 =
                            (kg == 0) ? (r1 + rowoff + 8) : (r1 + rowoff + 16);
                        __builtin_memcpy(&a0r, p0, 16);
                        __builtin_memcpy(&a1r, p1, 16);
                    }
                }
            }

            // ---- dots + gates (interleaved dual-accumulator, R13 form) ----
            unsigned hwd[12] = {hq0.x, hq0.y, hq0.z, hq0.w,
                                hq1.x, hq1.y, hq1.z, hq1.w,
                                hq2.x, hq2.y, hq2.z, hq2.w};
            float a0a = xgr[s8][0], a1a = xgr[s8][1], a2a = bh2;
            float a0b = 0.f, a1b = 0.f, a2b = 0.f;
            #pragma unroll
            for (int k = 0; k < 6; ++k) {
                f16x2 hv = asf16x2(hwd[k]);
                a0a = __builtin_amdgcn_fdot2(asf16x2(wrp[0][k]), hv, a0a, false);
                a1a = __builtin_amdgcn_fdot2(asf16x2(wrp[1][k]), hv, a1a, false);
                a2a = __builtin_amdgcn_fdot2(asf16x2(wrp[2][k]), hv, a2a, false);
            }
            #pragma unroll
            for (int k = 6; k < 12; ++k) {
                f16x2 hv = asf16x2(hwd[k]);
                a0b = __builtin_amdgcn_fdot2(asf16x2(wrp[0][k]), hv, a0b, false);
                a1b = __builtin_amdgcn_fdot2(asf16x2(wrp[1][k]), hv, a1b, false);
                a2b = __builtin_amdgcn_fdot2(asf16x2(wrp[2][k]), hv, a2b, false);
            }
            float r_ = sigm(a0a + a0b);
            float z_ = sigm(a1a + a1b);
            float n_ = tanh_(__builtin_fmaf(r_, a2a + a2b, xgr[s8][2]));
            float hnew = n_ + z_ * (hold - n_);
            hold = hnew;
            if constexpr (LAST) {
                int tg = dir ? (511 - (g * 8 + s8)) : (g * 8 + s8);
                if (u < 23 && tg == TT - 1)
                    lastbuf[bg * 48 + dir * 23 + u] = hnew;
            }
            hw[((s8 + 1) * 2 + bl) * 32 + u] = (_Float16)hnew;  // pads in 24..31
        }

        wbar();   // steps' hist writes precede store-phase reads

        // ---- cooperative coalesced store: raw f16 pair words, no cvt ----
        if constexpr (!LAST) {
            #pragma unroll
            for (int c = 0; c < 3; ++c) {
                unsigned w = ld4(&hw[ldsoff[c]]);
                if (cparr[c] == 11) w &= 0xFFFFu;   // col 23 := 0
                int tg = dir ? (511 - (g * 8 + sarr[c])) : (g * 8 + sarr[c]);
                *(unsigned*)(dstbase + (size_t)tg * 24 + 2 * cparr[c]) = w;
            }
        }
        // carry h into row 0 for next group (disjoint from store-phase rows)
        hw[bl * 32 + u] = (_Float16)hold;
        wbar();
        cur ^= 1;
    }
}

__global__ __launch_bounds__(256) void fc_kernel(
    const float* __restrict__ last, const float* __restrict__ fcw,
    const float* __restrict__ fcb, const float* __restrict__ ostd,
    const float* __restrict__ omean, float* __restrict__ out)
{
    int idx = blockIdx.x * 256 + threadIdx.x;
    if (idx >= BB * NOUT) return;
    int b = idx >> 3, o = idx & 7;
    float acc = fcb[o];
    const float* lr = last + b * 48;
    const float* wr = fcw + o * 46;
    #pragma unroll
    for (int i = 0; i < 46; i++) acc += lr[i] * wr[i];
    out[idx] = acc * ostd[o] + omean[o];
}

extern "C" void kernel_launch(void* const* d_in, const int* in_sizes, int n_in,
                              void* d_out, int out_size, void* d_ws,
                              size_t ws_size, hipStream_t stream)
{
    const float* x     = (const float*)d_in[0];
    const float* fmean = (const float*)d_in[1];
    const float* fstd  = (const float*)d_in[2];
    const float* omean = (const float*)d_in[3];
    const float* ostd  = (const float*)d_in[4];
    const float* wih0  = (const float*)d_in[5];
    const float* whh0  = (const float*)d_in[6];
    const float* bih0  = (const float*)d_in[7];
    const float* bhh0  = (const float*)d_in[8];
    const float* wihr  = (const float*)d_in[9];
    const float* whhr  = (const float*)d_in[10];
    const float* bihr  = (const float*)d_in[11];
    const float* bhhr  = (const float*)d_in[12];
    const float* fcw   = (const float*)d_in[13];
    const float* fcb   = (const float*)d_in[14];

    char* ws = (char*)d_ws;
    const size_t bufBytes = 2 * DSTRIDE * sizeof(unsigned short);  // 96 MiB
    unsigned short* buf0 = (unsigned short*)ws;
    unsigned short* buf1 = (unsigned short*)(ws + bufBytes);
    float* lastb         = (float*)(ws + 2 * bufBytes);

    dim3 grid(BB / 8, 2);

    gru_mfma<true, false><<<grid, 256, 0, stream>>>(
        x, fmean, fstd, wih0, whh0, bih0, bhh0, buf0, nullptr);
    gru_mfma<false, false><<<grid, 256, 0, stream>>>(
        buf0, nullptr, nullptr, wihr + 0 * 2 * 69 * 46, whhr + 0 * 2 * 69 * 23,
        bihr + 0 * 2 * 69, bhhr + 0 * 2 * 69, buf1, nullptr);
    gru_mfma<false, true><<<grid, 256, 0, stream>>>(
        buf1, nullptr, nullptr, wihr + 1 * 2 * 69 * 46, whhr + 1 * 2 * 69 * 23,
        bihr + 1 * 2 * 69, bhhr + 1 * 2 * 69, nullptr, lastb);
    fc_kernel<<<(BB * NOUT + 255) / 256, 256, 0, stream>>>(lastb, fcw, fcb, ostd,
                                                           omean, (float*)d_out);
}

// Round 9
// 616.365 us; speedup vs baseline: 1.0232x; 1.0073x over previous
//
#include <hip/hip_runtime.h>
#include <hip/hip_bf16.h>

constexpr int TT = 512, BB = 2048, NOUT = 8;
constexpr size_t DSTRIDE = (size_t)BB * TT * 24;   // f16 elems per dir region

typedef __attribute__((ext_vector_type(8))) _Float16 f16x8;
typedef __attribute__((ext_vector_type(4))) float f32x4;
typedef __attribute__((ext_vector_type(2))) _Float16 f16x2;

// fast device math: v_exp_f32 / v_rcp_f32 (1-ulp approx, no div sequence)
__device__ __forceinline__ float sigm(float x) {
    float e = __builtin_amdgcn_exp2f(x * -1.4426950408889634f);
    return __builtin_amdgcn_rcpf(1.f + e);
}
__device__ __forceinline__ float tanh_(float x) {
    float e = __builtin_amdgcn_exp2f(x * 2.8853900817779268f);
    return __builtin_fmaf(-2.f, __builtin_amdgcn_rcpf(e + 1.f), 1.f);
}
__device__ __forceinline__ f16x2 asf16x2(unsigned v) {
    f16x2 r; __builtin_memcpy(&r, &v, 4); return r;
}
// v_cvt_pkrtz_f16_f32 with a bit-cast to our f16x2 (builtin returns __fp16x2)
__device__ __forceinline__ f16x2 pkrtz(float a, float b) {
    auto p = __builtin_amdgcn_cvt_pkrtz(a, b);
    f16x2 r; __builtin_memcpy(&r, &p, 4); return r;
}
// TBAA-safe LDS loads: memcpy carries char aliasing -> may-alias the _Float16
// hist stores -> compiler preserves program order.
__device__ __forceinline__ uint4 ld16(const void* p) {
    uint4 r; __builtin_memcpy(&r, p, 16); return r;
}
__device__ __forceinline__ unsigned ld4(const void* p) {
    unsigned r; __builtin_memcpy(&r, p, 4); return r;
}
__device__ __forceinline__ void wbar() { __builtin_amdgcn_wave_barrier(); }

// R17: branch-free hot loop. R16's de-phase was null -> per-wave wall is
// intrinsic. VALUBusy arithmetic says ~156 instr/wave/step vs ~70 counted at
// source level: suspected bloat = per-step if(domfma)/if(doload) guards in
// the unrolled body (branch glue + exec-mask ops + sched fences). Fix: group
// body as an always-inlined lambda called with LITERAL flags -- main loop
// (62/64 groups) is fully unconditional; two epilogue groups specialize.
// a1r upper-half masking moved to the load sites (once per load, not per
// group). Math identical to R13/R16 (best measured 198.6-200.6us).
template <bool L0, bool LAST>
__global__ __launch_bounds__(256) void gru_mfma(
    const void* __restrict__ in_,        // L0: x [B][T][32] f32; else region0 (region1 at +DSTRIDE)
    const float* __restrict__ fmean, const float* __restrict__ fstd,
    const float* __restrict__ wih_g, const float* __restrict__ whh_g,
    const float* __restrict__ bih_g, const float* __restrict__ bhh_g,
    unsigned short* __restrict__ outbuf, float* __restrict__ lastbuf)
{
    constexpr int KIN = L0 ? 32 : 46;
    constexpr int KF  = L0 ? 1 : 2;
    constexpr int DSTR = 20;             // D-tile row stride (f32), 80B

    // [tile t<5][kslot<8][lane m<16][8 halves] staging for B-frags
    __shared__ __align__(16) _Float16  wih_lds[5 * 8 * 16 * 8];
    __shared__ __align__(16) _Float16  whh_h[80 * 24];       // W_hh f16
    __shared__ __align__(16) float     xg_s[4][2][80 * DSTR]; // per-wave D dbuf
    __shared__ __align__(16) _Float16  hist_h[4 * 9 * 2 * 32];  // h history f16
    __shared__ float bih_s[80], bhh_s[80];
    __shared__ __align__(16) float an_s[32], cn_s[32];

    const int tid = threadIdx.x, wv = tid >> 6, lane = tid & 63;
    const int bl = lane >> 5, u = lane & 31;
    const int m  = lane & 15, kg = lane >> 4;             // MFMA lane coords
    const int dir = blockIdx.y;
    const int bg  = blockIdx.x * 8 + wv * 2 + bl;

    const float* wih_d = wih_g + dir * 69 * KIN;
    const float* whh_d = whh_g + dir * 69 * 23;

    // ---- stage W_ih frags [t][kslot][m][8], col-remapped, zero-padded ----
    for (int idx = tid; idx < 5120; idx += 256) {
        int t = idx >> 10, r = idx & 1023;
        int kslot = r >> 7, mm = (r >> 3) & 15, j = r & 7;
        int row = t * 16 + mm, k = kslot * 8 + j;
        float v = 0.f;
        if (row < 69) {
            if constexpr (L0) {
                if (k < 32) v = wih_d[row * 32 + k];
            } else {
                if (k < 23) v = wih_d[row * 46 + k];                      // fwd
                else if (k >= 24 && k < 47) v = wih_d[row * 46 + k - 1];  // bwd
            }
        }
        wih_lds[idx] = (_Float16)v;
    }
    for (int idx = tid; idx < 80 * 24; idx += 256) {
        int j = idx / 24, k = idx - j * 24;
        whh_h[idx] = (j < 69 && k < 23) ? (_Float16)whh_d[j * 23 + k]
                                        : (_Float16)0.f;
    }
    for (int idx = tid; idx < 80; idx += 256) {
        bih_s[idx] = (idx < 69) ? bih_g[dir * 69 + idx] : 0.f;
        bhh_s[idx] = (idx < 69) ? bhh_g[dir * 69 + idx] : 0.f;
    }
    for (int idx = tid; idx < 4 * 9 * 2 * 32; idx += 256)
        hist_h[idx] = (_Float16)0.f;
    if (L0 && tid < 32) {
        float sd = fstd[tid];
        float sa = (sd == 0.f) ? 1.f : sd;        // std==0 -> 1
        float a  = (sa == 1.f) ? 0.f : 1.f / sa;  // adjusted std==1 -> zero
        an_s[tid] = a;
        cn_s[tid] = -fmean[tid] * a;
    }
    __syncthreads();   // only block-wide barrier

    // ---- per-lane W_hh rows (u, 23+u, 46+u) as f16 pairs -> 36 VGPRs ----
    unsigned wrp[3][12];
    float bh2;
    #pragma unroll
    for (int r = 0; r < 3; ++r) {
        int row = r * 23 + u;   // <= 77 < 80
        #pragma unroll
        for (int k = 0; k < 12; ++k)
            wrp[r][k] = ld4(&whh_h[row * 24 + 2 * k]);
    }
    bh2 = bhh_s[46 + u];   // n-row b_hh stays inside r*(...)
    // D-tile bias: b_ih (+ b_hh for r/z rows, which add outside the r gate)
    float bi5[5];
    #pragma unroll
    for (int t = 0; t < 5; ++t) {
        int n = t * 16 + m;
        bi5[t] = bih_s[n] + (n < 46 ? bhh_s[n] : 0.f);
    }

    // ---- B-fragments register-resident ----
    const f16x8* bfrag = (const f16x8*)wih_lds;   // [t*8+kslot][m]
    f16x8 bfr[5][KF];
    #pragma unroll
    for (int t = 0; t < 5; ++t)
        #pragma unroll
        for (int kf = 0; kf < KF; ++kf)
            bfr[t][kf] = bfrag[(t * 8 + kf * 4 + kg) * 16 + m];

    float an8[L0 ? 8 : 1], cn8[L0 ? 8 : 1];
    if constexpr (L0) {
        #pragma unroll
        for (int j = 0; j < 8; ++j) {
            an8[j] = an_s[kg * 8 + j];
            cn8[j] = cn_s[kg * 8 + j];
        }
    }

    float* db0 = &xg_s[wv][0][0];
    float* db1 = &xg_s[wv][1][0];
    _Float16* hw = &hist_h[wv * 9 * 2 * 32];
    const int ngroups = (LAST && dir == 1) ? 1 : 64;
    float hold = 0.f;

    // ---- store-phase lane constants (hoisted) ----
    int sarr[3], cparr[3], ldsoff[3];
    {
        int idx = lane & 31;
        #pragma unroll
        for (int c = 0; c < 3; ++c) {
            int p = idx + 32 * c;             // 0..95
            sarr[c]  = p / 12;
            cparr[c] = p - 12 * sarr[c];
            ldsoff[c] = ((sarr[c] + 1) * 2 + bl) * 32 + 2 * cparr[c];
        }
    }
    unsigned short* dstbase = nullptr;
    if constexpr (!LAST)
        dstbase = outbuf + dir * DSTRIDE + (size_t)bg * TT * 24;

    // A-row coords: m = bl_a*8 + tl
    const int bl_a = m >> 3, tl = m & 7;
    const int b_a  = blockIdx.x * 8 + wv * 2 + bl_a;

    const unsigned short* r0 = (const unsigned short*)in_;
    const unsigned short* r1 = r0 + DSTRIDE;

    float4 xraw0, xraw1;                 // L0 raw x
    f16x8 a0r, a1r;                      // !L0 f16 frags (a1r upper pre-masked)
    const f16x8 zz = {};

    // ---- load raw A data for group 0 ----
    {
        const int tg_a = dir ? (511 - tl) : tl;
        if constexpr (L0) {
            const float* xr = (const float*)in_ +
                              ((size_t)b_a * TT + tg_a) * 32 + kg * 8;
            xraw0 = *(const float4*)xr;
            xraw1 = *(const float4*)(xr + 4);
        } else {
            size_t rowoff = ((size_t)b_a * TT + tg_a) * 24;
            const unsigned short* p0 =
                (kg < 3) ? (r0 + rowoff + 8 * kg) : (r1 + rowoff);
            const unsigned short* p1 =
                (kg == 0) ? (r1 + rowoff + 8) : (r1 + rowoff + 16);
            __builtin_memcpy(&a0r, p0, 16);
            __builtin_memcpy(&a1r, p1, 16);
            if (kg >= 2) a1r = zz;
        }
    }

    // ---- prologue: MFMA for group 0 -> db0 (monolithic, once) ----
    {
        f32x4 acc0[5];
        #pragma unroll
        for (int t = 0; t < 5; ++t)
            acc0[t] = (f32x4){bi5[t], bi5[t], bi5[t], bi5[t]};
        if constexpr (L0) {
            float xv[8] = {xraw0.x, xraw0.y, xraw0.z, xraw0.w,
                           xraw1.x, xraw1.y, xraw1.z, xraw1.w};
            f16x8 afr0;
            #pragma unroll
            for (int j = 0; j < 4; ++j) {
                f16x2 p = pkrtz(xv[2 * j] * an8[2 * j] + cn8[2 * j],
                                xv[2 * j + 1] * an8[2 * j + 1] + cn8[2 * j + 1]);
                afr0[2 * j]     = p[0];
                afr0[2 * j + 1] = p[1];
            }
            #pragma unroll
            for (int t = 0; t < 5; ++t)
                acc0[t] = __builtin_amdgcn_mfma_f32_16x16x32_f16(afr0, bfr[t][0],
                                                                 acc0[t], 0, 0, 0);
        } else {
            #pragma unroll
            for (int t = 0; t < 5; ++t) {
                acc0[t] = __builtin_amdgcn_mfma_f32_16x16x32_f16(a0r, bfr[t][0],
                                                                 acc0[t], 0, 0, 0);
                acc0[t] = __builtin_amdgcn_mfma_f32_16x16x32_f16(a1r, bfr[t][1],
                                                                 acc0[t], 0, 0, 0);
            }
        }
        #pragma unroll
        for (int t = 0; t < 5; ++t)
            *(f32x4*)&db0[(t * 16 + m) * DSTR + kg * 4] = acc0[t];
    }
    // ---- load raw A data for group 1 ----
    if (1 < ngroups) {
        const int tg_a = dir ? (511 - (8 + tl)) : (8 + tl);
        if constexpr (L0) {
            const float* xr = (const float*)in_ +
                              ((size_t)b_a * TT + tg_a) * 32 + kg * 8;
            xraw0 = *(const float4*)xr;
            xraw1 = *(const float4*)(xr + 4);
        } else {
            size_t rowoff = ((size_t)b_a * TT + tg_a) * 24;
            const unsigned short* p0 =
                (kg < 3) ? (r0 + rowoff + 8 * kg) : (r1 + rowoff);
            const unsigned short* p1 =
                (kg == 0) ? (r1 + rowoff + 8) : (r1 + rowoff + 16);
            __builtin_memcpy(&a0r, p0, 16);
            __builtin_memcpy(&a1r, p1, 16);
            if (kg >= 2) a1r = zz;
        }
    }

    int cur = 0;
    f32x4 acc[5];
    f16x8 afr;

    // Group body; called with LITERAL domfma/doload -> the main loop's 62
    // instances are branch-free after constant folding + inlining.
    auto group_body = [&](int g, bool domfma, bool doload) {
        float* Dc = cur ? db1 : db0;
        float* Dn = cur ? db0 : db1;
        wbar();   // D(cur) writes precede in program order (in-order DS)

        // ---- prefetch this group's xg: 2x b128 per gate row (col-major D) --
        float xgr[8][3];
        #pragma unroll
        for (int c = 0; c < 3; ++c) {
            const f32x4 lo = *(const f32x4*)&Dc[(c * 23 + u) * DSTR + bl * 8];
            const f32x4 hi = *(const f32x4*)&Dc[(c * 23 + u) * DSTR + bl * 8 + 4];
            #pragma unroll
            for (int s = 0; s < 8; ++s)
                xgr[s][c] = (s < 4) ? lo[s] : hi[s - 4];
        }

        // ---- 8 scan steps with next-group work interleaved ----
        #pragma unroll
        for (int s8 = 0; s8 < 8; ++s8) {
            const _Float16* hr = &hw[(s8 * 2 + bl) * 32];   // prev h (f16)
            uint4 hq0 = ld16(hr);          // f16 0..7
            uint4 hq1 = ld16(hr + 8);      // f16 8..15
            uint4 hq2 = ld16(hr + 16);     // f16 16..23

            // ---- filler: independent work under hist-read latency ----
            if (s8 <= 4) {
                if (domfma) {
                    if constexpr (L0) {
                        if (s8 == 0) {
                            float xv[8] = {xraw0.x, xraw0.y, xraw0.z, xraw0.w,
                                           xraw1.x, xraw1.y, xraw1.z, xraw1.w};
                            #pragma unroll
                            for (int j = 0; j < 4; ++j) {
                                f16x2 p = pkrtz(
                                    xv[2 * j] * an8[2 * j] + cn8[2 * j],
                                    xv[2 * j + 1] * an8[2 * j + 1] + cn8[2 * j + 1]);
                                afr[2 * j]     = p[0];
                                afr[2 * j + 1] = p[1];
                            }
                        }
                        acc[s8] = (f32x4){bi5[s8], bi5[s8], bi5[s8], bi5[s8]};
                        acc[s8] = __builtin_amdgcn_mfma_f32_16x16x32_f16(
                            afr, bfr[s8][0], acc[s8], 0, 0, 0);
                    } else {
                        acc[s8] = (f32x4){bi5[s8], bi5[s8], bi5[s8], bi5[s8]};
                        acc[s8] = __builtin_amdgcn_mfma_f32_16x16x32_f16(
                            a0r, bfr[s8][0], acc[s8], 0, 0, 0);
                        acc[s8] = __builtin_amdgcn_mfma_f32_16x16x32_f16(
                            a1r, bfr[s8][1], acc[s8], 0, 0, 0);
                    }
                    if (s8 >= 1)
                        *(f32x4*)&Dn[((s8 - 1) * 16 + m) * DSTR + kg * 4] =
                            acc[s8 - 1];
                }
            } else if (s8 == 5) {
                if (domfma)
                    *(f32x4*)&Dn[(4 * 16 + m) * DSTR + kg * 4] = acc[4];
            } else if (s8 == 6) {
                if (doload) {
                    const int tg_n = dir ? (511 - ((g + 2) * 8 + tl))
                                         : ((g + 2) * 8 + tl);
                    if constexpr (L0) {
                        const float* xr = (const float*)in_ +
                                          ((size_t)b_a * TT + tg_n) * 32 + kg * 8;
                        xraw0 = *(const float4*)xr;
                        xraw1 = *(const float4*)(xr + 4);
                    } else {
                        size_t rowoff = ((size_t)b_a * TT + tg_n) * 24;
                        const unsigned short* p0 =
                            (kg < 3) ? (r0 + rowoff + 8 * kg) : (r1 + rowoff);
                        const unsigned short* p1 =
                            (kg == 0) ? (r1 + rowoff + 8) : (r1 + rowoff + 16);
                        __builtin_memcpy(&a0r, p0, 16);
                        __builtin_memcpy(&a1r, p1, 16);
                        if (kg >= 2) a1r = zz;
                    }
                }
            }

            // ---- dots + gates (interleaved dual-accumulator) ----
            unsigned hwd[12] = {hq0.x, hq0.y, hq0.z, hq0.w,
                                hq1.x, hq1.y, hq1.z, hq1.w,
                                hq2.x, hq2.y, hq2.z, hq2.w};
            float a0a = xgr[s8][0], a1a = xgr[s8][1], a2a = bh2;
            float a0b = 0.f, a1b = 0.f, a2b = 0.f;
            #pragma unroll
            for (int k = 0; k < 6; ++k) {
                f16x2 hv = asf16x2(hwd[k]);
                a0a = __builtin_amdgcn_fdot2(asf16x2(wrp[0][k]), hv, a0a, false);
                a1a = __builtin_amdgcn_fdot2(asf16x2(wrp[1][k]), hv, a1a, false);
                a2a = __builtin_amdgcn_fdot2(asf16x2(wrp[2][k]), hv, a2a, false);
            }
            #pragma unroll
            for (int k = 6; k < 12; ++k) {
                f16x2 hv = asf16x2(hwd[k]);
                a0b = __builtin_amdgcn_fdot2(asf16x2(wrp[0][k]), hv, a0b, false);
                a1b = __builtin_amdgcn_fdot2(asf16x2(wrp[1][k]), hv, a1b, false);
                a2b = __builtin_amdgcn_fdot2(asf16x2(wrp[2][k]), hv, a2b, false);
            }
            float r_ = sigm(a0a + a0b);
            float z_ = sigm(a1a + a1b);
            float n_ = tanh_(__builtin_fmaf(r_, a2a + a2b, xgr[s8][2]));
            float hnew = n_ + z_ * (hold - n_);
            hold = hnew;
            if constexpr (LAST) {
                int tg = dir ? (511 - (g * 8 + s8)) : (g * 8 + s8);
                if (u < 23 && tg == TT - 1)
                    lastbuf[bg * 48 + dir * 23 + u] = hnew;
            }
            hw[((s8 + 1) * 2 + bl) * 32 + u] = (_Float16)hnew;  // pads in 24..31
        }

        wbar();   // steps' hist writes precede store-phase reads

        // ---- cooperative coalesced store: raw f16 pair words, no cvt ----
        if constexpr (!LAST) {
            #pragma unroll
            for (int c = 0; c < 3; ++c) {
                unsigned w = ld4(&hw[ldsoff[c]]);
                if (cparr[c] == 11) w &= 0xFFFFu;   // col 23 := 0
                int tg = dir ? (511 - (g * 8 + sarr[c])) : (g * 8 + sarr[c]);
                *(unsigned*)(dstbase + (size_t)tg * 24 + 2 * cparr[c]) = w;
            }
        }
        // carry h into row 0 for next group (disjoint from store-phase rows)
        hw[bl * 32 + u] = (_Float16)hold;
        wbar();
        cur ^= 1;
    };

    // main loop: 62/64 groups with literal-true flags -> branch-free body
    for (int g = 0; g + 2 < ngroups; ++g)
        group_body(g, true, true);
    if (ngroups >= 2)
        group_body(ngroups - 2, true, false);
    group_body(ngroups - 1, false, false);
}

__global__ __launch_bounds__(256) void fc_kernel(
    const float* __restrict__ last, const float* __restrict__ fcw,
    const float* __restrict__ fcb, const float* __restrict__ ostd,
    const float* __restrict__ omean, float* __restrict__ out)
{
    int idx = blockIdx.x * 256 + threadIdx.x;
    if (idx >= BB * NOUT) return;
    int b = idx >> 3, o = idx & 7;
    float acc = fcb[o];
    const float* lr = last + b * 48;
    const float* wr = fcw + o * 46;
    #pragma unroll
    for (int i = 0; i < 46; i++) acc += lr[i] * wr[i];
    out[idx] = acc * ostd[o] + omean[o];
}

extern "C" void kernel_launch(void* const* d_in, const int* in_sizes, int n_in,
                              void* d_out, int out_size, void* d_ws,
                              size_t ws_size, hipStream_t stream)
{
    const float* x     = (const float*)d_in[0];
    const float* fmean = (const float*)d_in[1];
    const float* fstd  = (const float*)d_in[2];
    const float* omean = (const float*)d_in[3];
    const float* ostd  = (const float*)d_in[4];
    const float* wih0  = (const float*)d_in[5];
    const float* whh0  = (const float*)d_in[6];
    const float* bih0  = (const float*)d_in[7];
    const float* bhh0  = (const float*)d_in[8];
    const float* wihr  = (const float*)d_in[9];
    const float* whhr  = (const float*)d_in[10];
    const float* bihr  = (const float*)d_in[11];
    const float* bhhr  = (const float*)d_in[12];
    const float* fcw   = (const float*)d_in[13];
    const float* fcb   = (const float*)d_in[14];

    char* ws = (char*)d_ws;
    const size_t bufBytes = 2 * DSTRIDE * sizeof(unsigned short);  // 96 MiB
    unsigned short* buf0 = (unsigned short*)ws;
    unsigned short* buf1 = (unsigned short*)(ws + bufBytes);
    float* lastb         = (float*)(ws + 2 * bufBytes);

    dim3 grid(BB / 8, 2);

    gru_mfma<true, false><<<grid, 256, 0, stream>>>(
        x, fmean, fstd, wih0, whh0, bih0, bhh0, buf0, nullptr);
    gru_mfma<false, false><<<grid, 256, 0, stream>>>(
        buf0, nullptr, nullptr, wihr + 0 * 2 * 69 * 46, whhr + 0 * 2 * 69 * 23,
        bihr + 0 * 2 * 69, bhhr + 0 * 2 * 69, buf1, nullptr);
    gru_mfma<false, true><<<grid, 256, 0, stream>>>(
        buf1, nullptr, nullptr, wihr + 1 * 2 * 69 * 46, whhr + 1 * 2 * 69 * 23,
        bihr + 1 * 2 * 69, bhhr + 1 * 2 * 69, nullptr, lastb);
    fc_kernel<<<(BB * NOUT + 255) / 256, 256, 0, stream>>>(lastb, fcw, fcb, ostd,
                                                           omean, (float*)d_out);
}